// Round 1
// 5759.533 us; speedup vs baseline: 1.4632x; 1.4632x over previous
//
#include <hip/hip_runtime.h>
#include <stdint.h>

// RNN LM: embed->shift -> 2-layer tanh RNN (T=2048) -> logits vs embedding^T
//         -> log_softmax -> gather at tokens -> sum (scalar out).
//
// k_rnn R2: canary dataflow. h state arrays are plain f32, poisoned to
// 0xFFFFFFFF (NaN pattern — tanh can never produce it) by k_init each launch.
// Producers publish TWO adjacent columns per 8B relaxed-agent atomic store
// (pair via __shfl_down). Consumers spin per-thread (no per-round barrier),
// write LDS on arrival, then ONE __syncthreads per step (LDS double-buffered
// by parity). Dots use 4 accumulators to break the dependent-FMA chain.

#define TSEQ 2048
#define NVOCAB 32000
#define DEMB 512
#define DHID 1024
#define CAN 0xFFFFFFFFu

typedef __attribute__((ext_vector_type(8))) short short8;
typedef __attribute__((ext_vector_type(4))) float f32x4;
typedef unsigned long long u64;

__device__ __forceinline__ unsigned short f2bf(float f) {
  union { float f; unsigned u; } v; v.f = f;
  unsigned r = (v.u + 0x7FFFu + ((v.u >> 16) & 1u)) >> 16;
  return (unsigned short)r;
}

// ---------------- init: poison all slots; slot 0 = real zeros ----------------
__global__ void k_init(uint4* __restrict__ h1v4, uint4* __restrict__ h2v4) {
  const int n1 = (TSEQ + 1) * DHID / 4;
  const int n2 = (TSEQ + 1) * DEMB / 4;
  uint4 can; can.x = CAN; can.y = CAN; can.z = CAN; can.w = CAN;
  uint4 zer; zer.x = 0u; zer.y = 0u; zer.z = 0u; zer.w = 0u;
  const int stride = gridDim.x * blockDim.x;
  for (int i = blockIdx.x * blockDim.x + threadIdx.x; i < n1 + n2; i += stride) {
    if (i < n1) {
      h1v4[i] = (i < DHID / 4) ? zer : can;
    } else {
      int j = i - n1;
      h2v4[j] = (j < DEMB / 4) ? zer : can;
    }
  }
}

// ---------------- xW1[t][j] = b1[j] + sum_e inputs[t][e]*W1[e][j] ------------
__global__ __launch_bounds__(256) void k_xw1(const int* __restrict__ tok,
                                             const float* __restrict__ emb,
                                             const float* __restrict__ W1,
                                             const float* __restrict__ b1,
                                             float* __restrict__ xW1) {
  __shared__ float in_lds[16 * DEMB];
  const int tid = threadIdx.x;
  const int rb = blockIdx.x >> 2, cb = blockIdx.x & 3;
  const int t0 = rb * 16, j0 = cb * 256;
  for (int idx = tid; idx < 16 * 128; idx += 256) {
    int r = idx >> 7, q = idx & 127;
    int t = t0 + r;
    float4 v;
    if (t == 0) { v.x = 0.f; v.y = 0.f; v.z = 0.f; v.w = 0.f; }
    else        { v = *(const float4*)(emb + (size_t)tok[t - 1] * DEMB + q * 4); }
    *(float4*)&in_lds[r * DEMB + q * 4] = v;
  }
  __syncthreads();
  const int j = j0 + tid;
  float acc[16];
  {
    float bb = b1[j];
#pragma unroll
    for (int r = 0; r < 16; ++r) acc[r] = bb;
  }
  for (int k = 0; k < DEMB; k += 4) {
    const float* wp = W1 + (size_t)k * DHID + j;
    float w0 = wp[0], w1 = wp[DHID], w2 = wp[2 * DHID], w3 = wp[3 * DHID];
#pragma unroll
    for (int r = 0; r < 16; ++r) {
      float4 h = *(const float4*)&in_lds[r * DEMB + k];
      acc[r] += h.x * w0;
      acc[r] += h.y * w1;
      acc[r] += h.z * w2;
      acc[r] += h.w * w3;
    }
  }
#pragma unroll
  for (int r = 0; r < 16; ++r) xW1[(size_t)(t0 + r) * DHID + j] = acc[r];
}

// ---------------- persistent RNN, canary dataflow ----------------
// 48 WGs x 256 thr. WG 0..31: layer1, 32 cols each (c=tid>>3, s=tid&7, 128
// weights/thread in VGPRs). WG 32..47: layer2, 32 cols each (192 w/thread).
__global__ __launch_bounds__(256, 1) void k_rnn(const float* __restrict__ xW1,
                                                const float* __restrict__ U1,
                                                const float* __restrict__ W2,
                                                const float* __restrict__ U2,
                                                const float* __restrict__ b2,
                                                u64* __restrict__ h1v,
                                                u64* __restrict__ h2v,
                                                float* __restrict__ h2buf) {
  __shared__ float hl[2][1600];
  const int tid = threadIdx.x;
  const int wg = blockIdx.x;
  const int c = tid >> 3, s = tid & 7;

  if (wg < 32) {  // ---- layer 1: h1[t] = tanh(xW1[t] + h1[t-1]@U1) ----
    const int c0 = wg * 32;
    const int kb = s * 128;
    float w[128];
#pragma unroll
    for (int i = 0; i < 128; ++i) w[i] = U1[(size_t)(kb + i) * DHID + c0 + c];
    const int hbase = s * 132;               // 128 + 4 pad per slice
    const int pb = 4 * tid + ((4 * tid) >> 7) * 4;  // padded write base (16B aligned)
    const int myc = c0 + c;
    for (int st = 0; st < TSEQ; ++st) {
      float xv = xW1[(size_t)st * DHID + myc];  // independent: issues early
      float* hb = hl[st & 1];
      const u64* src = h1v + (size_t)st * (DHID / 2) + 2 * tid;
      u64 a0, a1;
      bool d0 = false, d1 = false;
      while (true) {  // per-thread spin, no WG round barrier
        u64 x0, x1;
        if (!d0) x0 = __hip_atomic_load(src + 0, __ATOMIC_RELAXED, __HIP_MEMORY_SCOPE_AGENT);
        if (!d1) x1 = __hip_atomic_load(src + 1, __ATOMIC_RELAXED, __HIP_MEMORY_SCOPE_AGENT);
        if (!d0 && (unsigned)(x0 >> 32) != CAN) { a0 = x0; d0 = true; }
        if (!d1 && (unsigned)(x1 >> 32) != CAN) { a1 = x1; d1 = true; }
        if (d0 && d1) break;
      }
      float4 t4;
      t4.x = __uint_as_float((unsigned)a0);
      t4.y = __uint_as_float((unsigned)(a0 >> 32));
      t4.z = __uint_as_float((unsigned)a1);
      t4.w = __uint_as_float((unsigned)(a1 >> 32));
      *(float4*)&hb[pb] = t4;
      __syncthreads();
      float ac0 = 0.f, ac1 = 0.f, ac2 = 0.f, ac3 = 0.f;
#pragma unroll
      for (int i = 0; i < 32; ++i) {
        float4 h = *(const float4*)&hb[hbase + 4 * i];
        ac0 += w[4 * i + 0] * h.x;
        ac1 += w[4 * i + 1] * h.y;
        ac2 += w[4 * i + 2] * h.z;
        ac3 += w[4 * i + 3] * h.w;
      }
      float acc = (ac0 + ac1) + (ac2 + ac3);
      acc += __shfl_xor(acc, 1);
      acc += __shfl_xor(acc, 2);
      acc += __shfl_xor(acc, 4);
      float hv = tanhf(xv + acc);            // all lanes (full sum via butterfly)
      float hv2 = __shfl_down(hv, 8);        // partner col c+1's value
      if (s == 0 && (c & 1) == 0) {
        u64 pk = ((u64)__float_as_uint(hv2) << 32) | (u64)__float_as_uint(hv);
        __hip_atomic_store(h1v + (size_t)(st + 1) * (DHID / 2) + (myc >> 1), pk,
                           __ATOMIC_RELAXED, __HIP_MEMORY_SCOPE_AGENT);
      }
    }
  } else {  // ---- layer 2: h2[j] = tanh(h1[j]@W2 + h2[j-1]@U2 + b2) ----
    const int c0 = (wg - 32) * 32;
    const int kb = s * 192;
    float w[192];
#pragma unroll
    for (int i = 0; i < 192; ++i) {
      int k = kb + i;
      const float* p = (k < DHID) ? (W2 + (size_t)k * DEMB) : (U2 + (size_t)(k - DHID) * DEMB);
      w[i] = p[c0 + c];
    }
    const int myc = c0 + c;
    const float bias = b2[myc];
    const int hbase = s * 196;               // 192 + 4 pad per slice
    const int pb = 6 * tid + (tid >> 5) * 4; // padded write base (6 f32, same block)
    for (int j2 = 0; j2 < TSEQ; ++j2) {
      float* hb = hl[j2 & 1];
      // u64 indices p=3*tid..3*tid+2 over concat [h1(512 u64) | h2(256 u64)]:
      // p<512 -> h1v[(j2+1)*512 + p], else h2v[j2*256 + p-512]
      const u64* sp[3];
#pragma unroll
      for (int q = 0; q < 3; ++q) {
        int p = 3 * tid + q;
        sp[q] = (p < DHID / 2) ? (h1v + (size_t)(j2 + 1) * (DHID / 2) + p)
                               : (h2v + (size_t)j2 * (DEMB / 2) + (p - DHID / 2));
      }
      u64 a[3];
      bool dn[3];
#pragma unroll
      for (int q = 0; q < 3; ++q) dn[q] = false;
      while (true) {  // per-thread spin
        u64 x[3];
#pragma unroll
        for (int q = 0; q < 3; ++q)
          if (!dn[q]) x[q] = __hip_atomic_load(sp[q], __ATOMIC_RELAXED, __HIP_MEMORY_SCOPE_AGENT);
#pragma unroll
        for (int q = 0; q < 3; ++q)
          if (!dn[q] && (unsigned)(x[q] >> 32) != CAN) { a[q] = x[q]; dn[q] = true; }
        if (dn[0] && dn[1] && dn[2]) break;
      }
      float2 f0, f1, f2;
      f0.x = __uint_as_float((unsigned)a[0]); f0.y = __uint_as_float((unsigned)(a[0] >> 32));
      f1.x = __uint_as_float((unsigned)a[1]); f1.y = __uint_as_float((unsigned)(a[1] >> 32));
      f2.x = __uint_as_float((unsigned)a[2]); f2.y = __uint_as_float((unsigned)(a[2] >> 32));
      *(float2*)&hb[pb] = f0;
      *(float2*)&hb[pb + 2] = f1;
      *(float2*)&hb[pb + 4] = f2;
      __syncthreads();
      float ac0 = 0.f, ac1 = 0.f, ac2 = 0.f, ac3 = 0.f;
#pragma unroll
      for (int i = 0; i < 48; ++i) {
        float4 h = *(const float4*)&hb[hbase + 4 * i];
        ac0 += w[4 * i + 0] * h.x;
        ac1 += w[4 * i + 1] * h.y;
        ac2 += w[4 * i + 2] * h.z;
        ac3 += w[4 * i + 3] * h.w;
      }
      float acc = (ac0 + ac1) + (ac2 + ac3);
      acc += __shfl_xor(acc, 1);
      acc += __shfl_xor(acc, 2);
      acc += __shfl_xor(acc, 4);
      float hv = tanhf(acc + bias);
      float hv2 = __shfl_down(hv, 8);
      if (s == 0 && (c & 1) == 0) {
        u64 pk = ((u64)__float_as_uint(hv2) << 32) | (u64)__float_as_uint(hv);
        __hip_atomic_store(h2v + (size_t)(j2 + 1) * (DEMB / 2) + (myc >> 1), pk,
                           __ATOMIC_RELAXED, __HIP_MEMORY_SCOPE_AGENT);
        float2 st2; st2.x = hv; st2.y = hv2;
        *(float2*)&h2buf[(size_t)(j2 + 1) * DEMB + myc] = st2;
      }
    }
  }
}

// ---------------- f32 -> bf16 casts (embedding + h2 history) ----------------
__global__ void k_conv(const float* __restrict__ emb, const float* __restrict__ h2f,
                       unsigned short* __restrict__ embB, unsigned short* __restrict__ h2b) {
  const int n1 = NVOCAB * DEMB / 4;
  const int n2 = TSEQ * DEMB / 4;
  const int stride = gridDim.x * blockDim.x;
  for (int i = blockIdx.x * blockDim.x + threadIdx.x; i < n1 + n2; i += stride) {
    float4 v;
    if (i < n1) v = ((const float4*)emb)[i];
    else        v = ((const float4*)h2f)[i - n1];
    ushort4 o;
    o.x = f2bf(v.x); o.y = f2bf(v.y); o.z = f2bf(v.z); o.w = f2bf(v.w);
    if (i < n1) ((ushort4*)embB)[i] = o;
    else        ((ushort4*)h2b)[i - n1] = o;
  }
}

// ---------------- fused logits GEMM + online softmax stats ----------------
__global__ __launch_bounds__(256, 1) void k_logits(const unsigned short* __restrict__ Ab,
                                                   const unsigned short* __restrict__ Bb,
                                                   float* __restrict__ pmax,
                                                   float* __restrict__ psum) {
  extern __shared__ char smem_dyn[];
  unsigned short* As = (unsigned short*)smem_dyn;       // 128*512*2 = 131072 B
  float* sstat = (float*)(smem_dyn + 131072);           // 4*128*2 f32
  const int tid = threadIdx.x;
  const int rb = blockIdx.x >> 4, ch = blockIdx.x & 15;
  const int r0 = rb * 128, v0 = ch * 2000;
  for (int idx = tid; idx < 128 * 64; idx += 256) {
    int row = idx >> 6, kq = idx & 63;
    uint4 v = *(const uint4*)(Ab + (size_t)(r0 + row) * DEMB + kq * 8);
    int byte = (row * 1024 + kq * 16) ^ ((row & 7) << 4);
    *(uint4*)((char*)As + byte) = v;
  }
  __syncthreads();
  const int wv = tid >> 6, lane = tid & 63;
  const int col = lane & 15, kg = lane >> 4;
  f32x4 rmax[8], rsum[8];
#pragma unroll
  for (int t = 0; t < 8; ++t) { rmax[t] = (f32x4)(-3.0e38f); rsum[t] = (f32x4)(0.f); }

  for (int strip = wv; strip < 125; strip += 4) {
    const unsigned short* bp = Bb + (size_t)(v0 + strip * 16 + col) * DEMB + kg * 8;
    f32x4 acc[8];
#pragma unroll
    for (int t = 0; t < 8; ++t) acc[t] = (f32x4)(0.f);
#pragma unroll
    for (int ks = 0; ks < 16; ++ks) {
      short8 bfrag = *(const short8*)(bp + ks * 32);
#pragma unroll
      for (int t = 0; t < 8; ++t) {
        int row = t * 16 + col;
        int byte = (row * 1024 + ks * 64 + kg * 16) ^ ((row & 7) << 4);
        short8 afrag = *(const short8*)((const char*)As + byte);
        acc[t] = __builtin_amdgcn_mfma_f32_16x16x32_bf16(afrag, bfrag, acc[t], 0, 0, 0);
      }
    }
#pragma unroll
    for (int t = 0; t < 8; ++t) {
      f32x4 v = acc[t];
      f32x4 mx = v;
#pragma unroll
      for (int d = 1; d < 16; d <<= 1) {
        mx.x = fmaxf(mx.x, __shfl_xor(mx.x, d));
        mx.y = fmaxf(mx.y, __shfl_xor(mx.y, d));
        mx.z = fmaxf(mx.z, __shfl_xor(mx.z, d));
        mx.w = fmaxf(mx.w, __shfl_xor(mx.w, d));
      }
      f32x4 nm;
      nm.x = fmaxf(rmax[t].x, mx.x);
      nm.y = fmaxf(rmax[t].y, mx.y);
      nm.z = fmaxf(rmax[t].z, mx.z);
      nm.w = fmaxf(rmax[t].w, mx.w);
      f32x4 e;
      e.x = __expf(v.x - nm.x); e.y = __expf(v.y - nm.y);
      e.z = __expf(v.z - nm.z); e.w = __expf(v.w - nm.w);
#pragma unroll
      for (int d = 1; d < 16; d <<= 1) {
        e.x += __shfl_xor(e.x, d);
        e.y += __shfl_xor(e.y, d);
        e.z += __shfl_xor(e.z, d);
        e.w += __shfl_xor(e.w, d);
      }
      rsum[t].x = rsum[t].x * __expf(rmax[t].x - nm.x) + e.x;
      rsum[t].y = rsum[t].y * __expf(rmax[t].y - nm.y) + e.y;
      rsum[t].z = rsum[t].z * __expf(rmax[t].z - nm.z) + e.z;
      rsum[t].w = rsum[t].w * __expf(rmax[t].w - nm.w) + e.w;
      rmax[t] = nm;
    }
  }
  if (col == 0) {
#pragma unroll
    for (int t = 0; t < 8; ++t) {
#pragma unroll
      for (int r = 0; r < 4; ++r) {
        int row = t * 16 + kg * 4 + r;
        sstat[(wv * 128 + row) * 2 + 0] = rmax[t][r];
        sstat[(wv * 128 + row) * 2 + 1] = rsum[t][r];
      }
    }
  }
  __syncthreads();
  if (tid < 128) {
    float m = -3.0e38f, ssum = 0.f;
#pragma unroll
    for (int w2 = 0; w2 < 4; ++w2) {
      float pm = sstat[(w2 * 128 + tid) * 2 + 0];
      float ps = sstat[(w2 * 128 + tid) * 2 + 1];
      float nm2 = fmaxf(m, pm);
      ssum = ssum * __expf(m - nm2) + ps * __expf(pm - nm2);
      m = nm2;
    }
    pmax[(size_t)(r0 + tid) * 16 + ch] = m;
    psum[(size_t)(r0 + tid) * 16 + ch] = ssum;
  }
}

// ---------------- target logit in f32: dot(h2[t], emb[tok[t]]) ----------------
__global__ __launch_bounds__(256) void k_tlogit(const int* __restrict__ tok,
                                                const float* __restrict__ emb,
                                                const float* __restrict__ h2buf,
                                                float* __restrict__ tlog) {
  const int wv = threadIdx.x >> 6, lane = threadIdx.x & 63;
  const int wgid = blockIdx.x * 4 + wv;
  for (int t = wgid; t < TSEQ; t += 128) {
    const float* hp = h2buf + (size_t)(t + 1) * DEMB + lane * 8;
    const float* ep = emb + (size_t)tok[t] * DEMB + lane * 8;
    float4 h0 = *(const float4*)hp, h1v = *(const float4*)(hp + 4);
    float4 e0 = *(const float4*)ep, e1v = *(const float4*)(ep + 4);
    float d = h0.x * e0.x + h0.y * e0.y + h0.z * e0.z + h0.w * e0.w +
              h1v.x * e1v.x + h1v.y * e1v.y + h1v.z * e1v.z + h1v.w * e1v.w;
    for (int m = 1; m < 64; m <<= 1) d += __shfl_xor(d, m);
    if (lane == 0) tlog[t] = d;
  }
}

// ---------------- final: sum_t (tlogit - lse) ----------------
__global__ void k_final(const float* __restrict__ pmax, const float* __restrict__ psum,
                        const float* __restrict__ tlog, float* __restrict__ out) {
  __shared__ float red[4];
  float local = 0.f;
  for (int t = threadIdx.x; t < TSEQ; t += 256) {
    float m = -3.0e38f, s = 0.f;
#pragma unroll
    for (int c = 0; c < 16; ++c) {
      float pm = pmax[t * 16 + c], ps = psum[t * 16 + c];
      float nm = fmaxf(m, pm);
      s = s * __expf(m - nm) + ps * __expf(pm - nm);
      m = nm;
    }
    local += tlog[t] - (m + __logf(s));
  }
  for (int d = 1; d < 64; d <<= 1) local += __shfl_xor(local, d);
  if ((threadIdx.x & 63) == 0) red[threadIdx.x >> 6] = local;
  __syncthreads();
  if (threadIdx.x == 0) out[0] = red[0] + red[1] + red[2] + red[3];
}

// ---------------- host ----------------
extern "C" void kernel_launch(void* const* d_in, const int* in_sizes, int n_in,
                              void* d_out, int out_size, void* d_ws, size_t ws_size,
                              hipStream_t stream) {
  (void)in_sizes; (void)n_in; (void)out_size; (void)ws_size;
  const int*   tok = (const int*)d_in[0];
  const float* emb = (const float*)d_in[1];
  const float* W1  = (const float*)d_in[2];
  const float* U1  = (const float*)d_in[3];
  const float* b1  = (const float*)d_in[4];
  const float* W2  = (const float*)d_in[5];
  const float* U2  = (const float*)d_in[6];
  const float* b2  = (const float*)d_in[7];
  float* out = (float*)d_out;

  char* ws = (char*)d_ws;
  size_t off = 0;
  auto alloc = [&](size_t bytes) {
    char* p = ws + off;
    off = (off + bytes + 255) & ~(size_t)255;
    return p;
  };
  float* h2buf = (float*)alloc((size_t)(TSEQ + 1) * DEMB * 4);
  unsigned short* h2b = (unsigned short*)alloc((size_t)TSEQ * DEMB * 2);
  float* pmax = (float*)alloc((size_t)TSEQ * 16 * 4);
  float* psum = (float*)alloc((size_t)TSEQ * 16 * 4);
  float* tlog = (float*)alloc((size_t)TSEQ * 4);
  // big region: [h2v][h1v][xW1] during k_rnn; embB (32.77MB) overlays from
  // offset 0 afterwards. Safe because k_init re-poisons all h slots at the
  // start of every launch before k_rnn runs.
  size_t sz_h2v = (size_t)(TSEQ + 1) * DEMB * 4;   //  4,196,352
  size_t sz_h1v = (size_t)(TSEQ + 1) * DHID * 4;   //  8,392,704
  size_t sz_xw1 = (size_t)TSEQ * DHID * 4;         //  8,388,608
  size_t sz_embB = (size_t)NVOCAB * DEMB * 2;      // 32,768,000
  size_t big_sz = sz_h2v + sz_h1v + sz_xw1;
  if (sz_embB > big_sz) big_sz = sz_embB;
  char* big = alloc(big_sz);
  float* h2v = (float*)big;
  float* h1v = (float*)(big + sz_h2v);
  float* xW1 = (float*)(big + sz_h2v + sz_h1v);
  unsigned short* embB = (unsigned short*)big;

  k_init<<<dim3(512), dim3(256), 0, stream>>>((uint4*)h1v, (uint4*)h2v);
  k_xw1<<<dim3(512), dim3(256), 0, stream>>>(tok, emb, W1, b1, xW1);
  k_rnn<<<dim3(48), dim3(256), 0, stream>>>(xW1, U1, W2, U2, b2,
                                            (u64*)h1v, (u64*)h2v, h2buf);
  k_conv<<<dim3(2048), dim3(256), 0, stream>>>(emb, h2buf + DEMB, embB, h2b);
  k_logits<<<dim3(256), dim3(256), 135168, stream>>>(h2b, embB, pmax, psum);
  k_tlogit<<<dim3(32), dim3(256), 0, stream>>>(tok, emb, h2buf, tlog);
  k_final<<<dim3(1), dim3(256), 0, stream>>>(pmax, psum, tlog, out);
}